// Round 1
// baseline (16.756 us; speedup 1.0000x reference)
//
#include <hip/hip_runtime.h>

#define TPB 256
#define KSEL 8

// Pack (value, index) into a single u64 key whose unsigned order matches
// "larger value wins; on equal value, smaller index wins" (jnp.argmax tie rule).
__device__ __forceinline__ unsigned long long make_key(float v, unsigned int idx) {
    unsigned int u = __float_as_uint(v);
    unsigned int ord = (u & 0x80000000u) ? ~u : (u | 0x80000000u); // monotone map
    return ((unsigned long long)ord << 32) | (unsigned long long)(~idx);
}

__device__ __forceinline__ unsigned long long kmax(unsigned long long a, unsigned long long b) {
    return a > b ? a : b;
}

// Kernel 1: per-block top-8 of point_weight. Each thread owns <=1 float4 (+1 tail
// scalar in block 0). Block-wide: 8 passes of {local max over candidate regs ->
// wave shfl reduce -> cross-wave LDS reduce -> invalidate winner by key equality}.
__global__ __launch_bounds__(TPB) void topk_scan(const float* __restrict__ pw, int N,
                                                 unsigned long long* __restrict__ ws_keys) {
    __shared__ unsigned long long s_wave[TPB / 64];
    __shared__ unsigned long long s_win;
    __shared__ unsigned long long s_sel[KSEL];

    const int tid  = threadIdx.x;
    const int lane = tid & 63;
    const int wave = tid >> 6;
    const int N4   = N >> 2;
    const int gid  = blockIdx.x * TPB + tid;

    unsigned long long cand[5] = {0ull, 0ull, 0ull, 0ull, 0ull};
    if (gid < N4) {
        const float4 v = reinterpret_cast<const float4*>(pw)[gid];
        const unsigned int base = (unsigned int)gid * 4u;
        cand[0] = make_key(v.x, base + 0u);
        cand[1] = make_key(v.y, base + 1u);
        cand[2] = make_key(v.z, base + 2u);
        cand[3] = make_key(v.w, base + 3u);
    }
    // tail (N % 4) handled by block 0
    if (blockIdx.x == 0) {
        int t = N4 * 4 + tid;
        if (t < N) cand[4] = make_key(pw[t], (unsigned int)t);
    }

    for (int p = 0; p < KSEL; ++p) {
        unsigned long long k = cand[0];
        #pragma unroll
        for (int c = 1; c < 5; ++c) k = kmax(k, cand[c]);
        #pragma unroll
        for (int o = 32; o > 0; o >>= 1) k = kmax(k, __shfl_down(k, o));
        if (lane == 0) s_wave[wave] = k;
        __syncthreads();
        if (tid == 0) {
            unsigned long long w = s_wave[0];
            #pragma unroll
            for (int i = 1; i < TPB / 64; ++i) w = kmax(w, s_wave[i]);
            s_win = w;
            s_sel[p] = w;
        }
        __syncthreads();
        const unsigned long long w = s_win;
        #pragma unroll
        for (int c = 0; c < 5; ++c) if (cand[c] == w) cand[c] = 0ull;
    }

    if (tid < KSEL) ws_keys[blockIdx.x * KSEL + tid] = s_sel[tid];
}

// Kernel 2: merge <=512 candidate keys to global top-8, then
// out[b,h] = bias[h] + sum_k x[b, idx_k] * W[idx_k, h].
__global__ __launch_bounds__(TPB) void topk_merge_out(
        const unsigned long long* __restrict__ ws_keys, int nkeys,
        const float* __restrict__ x, const float* __restrict__ w,
        const float* __restrict__ bias, float* __restrict__ out,
        int N, int H, int B) {
    __shared__ unsigned long long s_wave[TPB / 64];
    __shared__ unsigned long long s_win;
    __shared__ int s_idx[KSEL];
    __shared__ float s_x[16][KSEL];   // B <= 16

    const int tid  = threadIdx.x;
    const int lane = tid & 63;
    const int wave = tid >> 6;

    unsigned long long cand[2] = {0ull, 0ull};
    if (tid < nkeys)        cand[0] = ws_keys[tid];
    if (tid + TPB < nkeys)  cand[1] = ws_keys[tid + TPB];

    for (int p = 0; p < KSEL; ++p) {
        unsigned long long k = kmax(cand[0], cand[1]);
        #pragma unroll
        for (int o = 32; o > 0; o >>= 1) k = kmax(k, __shfl_down(k, o));
        if (lane == 0) s_wave[wave] = k;
        __syncthreads();
        if (tid == 0) {
            unsigned long long win = s_wave[0];
            #pragma unroll
            for (int i = 1; i < TPB / 64; ++i) win = kmax(win, s_wave[i]);
            s_win = win;
            s_idx[p] = (int)(~(unsigned int)(win & 0xffffffffull));
        }
        __syncthreads();
        const unsigned long long win = s_win;
        if (cand[0] == win) cand[0] = 0ull;
        if (cand[1] == win) cand[1] = 0ull;
    }

    __syncthreads();
    // gather the 8*B needed x values
    if (tid < B * KSEL) {
        const int b = tid / KSEL, k = tid % KSEL;
        s_x[b][k] = x[(long)b * N + s_idx[k]];
    }
    __syncthreads();

    for (int h = tid; h < H; h += TPB) {
        float wv[KSEL];
        #pragma unroll
        for (int k = 0; k < KSEL; ++k) wv[k] = w[(long)s_idx[k] * H + h];
        const float bv = bias[h];
        for (int b = 0; b < B; ++b) {
            float acc = bv;
            #pragma unroll
            for (int k = 0; k < KSEL; ++k) acc += s_x[b][k] * wv[k];
            out[(long)b * H + h] = acc;
        }
    }
}

extern "C" void kernel_launch(void* const* d_in, const int* in_sizes, int n_in,
                              void* d_out, int out_size, void* d_ws, size_t ws_size,
                              hipStream_t stream) {
    const float* x    = (const float*)d_in[0];
    const float* pw   = (const float*)d_in[1];
    const float* w    = (const float*)d_in[2];
    const float* bias = (const float*)d_in[3];
    float* out = (float*)d_out;

    const int N = in_sizes[1];           // 56564
    const int H = in_sizes[3];           // 256
    const int B = in_sizes[0] / N;       // 8
    const int N4 = N >> 2;
    const int nblk = (N4 + TPB - 1) / TPB;   // 56 for N=56564 (<=64 keeps merge in 2 regs)

    unsigned long long* keys = (unsigned long long*)d_ws;

    topk_scan<<<nblk, TPB, 0, stream>>>(pw, N, keys);
    topk_merge_out<<<1, TPB, 0, stream>>>(keys, nblk * KSEL, x, w, bias, out, N, H, B);
}